// Round 9
// baseline (377.177 us; speedup 1.0000x reference)
//
#include <hip/hip_runtime.h>
#include <math.h>

#define B_ 64
#define N_ 512
#define R_ (B_*N_)                  // 32768 rows
#define INV_S 0.9995003746877732f   // 1/sqrt(1+1e-3)

__device__ __forceinline__ float fast_tanh(float y){
  return 1.f - 2.f*__builtin_amdgcn_rcpf(1.f + __expf(2.f*y));
}
__device__ __forceinline__ float fast_sigmoid(float v){
  return __builtin_amdgcn_rcpf(1.f + __expf(-v));
}

// ---------------------------------------------------------------------------
// Persistent GNN: ONE kernel runs all 5 layers. 256 blocks x 512 threads.
// Block g=(b<<2)|q owns rows [q*128, q*128+128) of batch b; its x tile
// lives in LDS across ALL layers (no global x round-trips; only coords go
// through a double-buffered global cbuf). Per-batch dependency (4 blocks)
// is enforced with device-scope flag barriers; ws poison 0xAA = negative
// int, so flags need no init (stored values 1..4 are all > poison).
// Co-residency: LDS 79.5 KB <= 160 KB/CU -> 1 block/CU guaranteed for all
// 256 blocks => spin barriers cannot deadlock.
// Layer phases: [wait] -> stage cl(512 coords)+A(lo/hi, LDS) -> S/T (each
// half: 64 j x 4 i-chunk waves) -> GEMM (thread = 4 rows x 4 outs x 2 mats,
// x from LDS xt stride 68 = 2-way-conflict-free) -> epilogue in-place into
// xt + coords->cbuf (L<4) or full x->global (L==4) -> flag store.
// ---------------------------------------------------------------------------
__global__ __launch_bounds__(512, 4) void gnn_all(
    const float* __restrict__ xx,
    const float* __restrict__ emb1, const float* __restrict__ emb2,
    const float* __restrict__ emb3,
    const float* __restrict__ A0, const float* __restrict__ b0,
    const float* __restrict__ Ar, const float* __restrict__ br,
    const float* __restrict__ bng, const float* __restrict__ bnb,
    float* __restrict__ xA, float4* __restrict__ cbuf,
    int* __restrict__ flags)
{
  __shared__ float4 cl[512];          // 8 KB
  __shared__ float alo[64*64];        // 16 KB
  __shared__ float ahi[64*64];        // 16 KB
  __shared__ float xt[128*68];        // 34 KB (stride 68: 16B-aligned rows)
  __shared__ float spart[512], tpart[512];   // 4 KB
  __shared__ float scl[128], tcl[128], ml[128];

  int tid = threadIdx.x;
  int g = blockIdx.x;
  int b = g >> 2, q = g & 3;
  int rbase = b*N_;
  int row0 = q*128;                   // first row (within batch) of this block
  int h = tid >> 8, t = tid & 255;    // half (64-row sub-tile), half-local id

  // ---- once: mask + L0 x tile (128 rows, 33 feats + zero pad) ----
  if (tid < 128){
    int r = rbase + row0 + tid;
    const float* row = xx + (size_t)r*30;
    float v[30];
#pragma unroll
    for (int i=0;i<30;i++) v[i] = row[i];
    int i1 = (int)fabsf(v[27]);
    int i2 = (int)fabsf(v[28]);
    int i3 = (int)fabsf(v[29]);
    float* o = &xt[tid*68];
    o[0]=emb1[i1*2+0]; o[1]=emb1[i1*2+1];
    o[2]=emb2[i2*2+0]; o[3]=emb2[i2*2+1];
    o[4]=emb3[i3*2+0]; o[5]=emb3[i3*2+1];
#pragma unroll
    for (int i=0;i<27;i++) o[6+i] = v[i];
    o[33]=0.f; o[34]=0.f; o[35]=0.f;
    ml[tid] = v[0];
  }

  for (int L = 0; L < 5; L++){
    const float* A    = (L==0)? A0 : (Ar + (size_t)(L-1)*129*64);
    const float* bias = (L==0)? b0 : (br + (L-1)*64);
    const float* gam  = bng + L*64;
    const float* bet  = bnb + L*64;
    int K  = (L==0)? 33 : 64;
    int KP = (L==0)? 36 : 64;
    float4* cb_in  = cbuf + (size_t)(L&1)*R_;
    float4* cb_out = cbuf + (size_t)((L+1)&1)*R_;

    // ---- per-batch barrier: wait for all 4 blocks of batch b at layer L ----
    if (L > 0){
      if (tid < 4){
        while (__hip_atomic_load(&flags[b*4+tid], __ATOMIC_ACQUIRE,
                                 __HIP_MEMORY_SCOPE_AGENT) < L){
          __builtin_amdgcn_s_sleep(1);
        }
      }
    }
    __syncthreads();   // also: epilogue of L-1 fully done (xt/alo reusable)

    // ---- stage coords of all 512 rows of the batch ----
    if (L == 0){
      {
        const float* row = xx + (size_t)(rbase+tid)*30;
        cl[tid] = make_float4(row[25], row[26], 0.f, 0.f);
      }
    } else {
      cl[tid] = cb_in[rbase + tid];
    }
    // ---- stage A lo/hi into LDS ----
    if (L == 0){
      for (int idx = tid; idx < 36*64; idx += 512){
        int f = idx >> 6;
        alo[idx] = (f < 33)? A[idx] : 0.f;
        ahi[idx] = (f < 33)? A[33*64 + idx] : 0.f;
      }
    } else {
      const float4* A4 = (const float4*)A;
      float4* alo4 = (float4*)alo;
      float4* ahi4 = (float4*)ahi;
      for (int idx = tid; idx < 1024; idx += 512){
        alo4[idx] = A4[idx];
        ahi4[idx] = A4[1024+idx];
      }
    }
    __syncthreads();

    // ---- S/T: per half, 64 j's x 4 i-chunk waves ----
    {
      int jj = t & 63, ic = t >> 6;
      float4 cj = cl[row0 + h*64 + jj];
      float Ss=0.f, Ts=0.f;
      int base = ic*128;
#pragma unroll 8
      for (int i=0;i<128;i++){
        float4 ci = cl[base+i];
        float d0=cj.x-ci.x, d1=cj.y-ci.y, d2=cj.z-ci.z, d3=cj.w-ci.w;
        float dist = d0*d0+d1*d1+d2*d2+d3*d3;
        float w = __expf(-10.f*dist);
        Ss += w; Ts += dist*w;
      }
      spart[tid] = Ss; tpart[tid] = Ts;
    }
    __syncthreads();
    if (tid < 128){
      int hh = tid >> 6;
      int base = hh*256 + (tid & 63);
      float S = spart[base] + spart[base+64] + spart[base+128] + spart[base+192];
      float T = tpart[base] + tpart[base+64] + tpart[base+128] + tpart[base+192];
      float m = ml[tid];
      scl[tid] = m*S - 1.f;
      tcl[tid] = m*T;
    }
    __syncthreads();

    // ---- GEMM: thread = 4 rows x 4 outs, two matrices, x from LDS ----
    int o0 = (t & 15)*4, rloc = (t >> 4)*4;
    int lr0 = h*64 + rloc;
    float4 acc1[4], acc2[4];
#pragma unroll
    for (int rr=0;rr<4;rr++){
      acc1[rr] = make_float4(0.f,0.f,0.f,0.f);
      acc2[rr] = make_float4(0.f,0.f,0.f,0.f);
    }
#pragma unroll 2
    for (int kc = 0; kc < KP; kc += 4){
      float4 a1[4], a2[4], xv[4];
#pragma unroll
      for (int uu=0;uu<4;uu++){
        a1[uu] = *(const float4*)&alo[(kc+uu)*64 + o0];
        a2[uu] = *(const float4*)&ahi[(kc+uu)*64 + o0];
      }
#pragma unroll
      for (int rr=0;rr<4;rr++)
        xv[rr] = *(const float4*)&xt[(lr0+rr)*68 + kc];
#pragma unroll
      for (int uu=0;uu<4;uu++){
#pragma unroll
        for (int rr=0;rr<4;rr++){
          float xu = ((const float*)&xv[rr])[uu];
          acc1[rr].x = fmaf(xu, a1[uu].x, acc1[rr].x);
          acc1[rr].y = fmaf(xu, a1[uu].y, acc1[rr].y);
          acc1[rr].z = fmaf(xu, a1[uu].z, acc1[rr].z);
          acc1[rr].w = fmaf(xu, a1[uu].w, acc1[rr].w);
          acc2[rr].x = fmaf(xu, a2[uu].x, acc2[rr].x);
          acc2[rr].y = fmaf(xu, a2[uu].y, acc2[rr].y);
          acc2[rr].z = fmaf(xu, a2[uu].z, acc2[rr].z);
          acc2[rr].w = fmaf(xu, a2[uu].w, acc2[rr].w);
        }
      }
    }

    float4 alast = *(const float4*)&A[(size_t)2*K*64 + o0];
    float4 bo = *(const float4*)&bias[o0];
    float4 go = *(const float4*)&gam[o0];
    float4 be = *(const float4*)&bet[o0];
    float4 res[4];
#pragma unroll
    for (int rr=0;rr<4;rr++){
      int lr = lr0 + rr;
      float sc = scl[lr], tc = tcl[lr], m = ml[lr];
      float4 v;
      v.x = (acc1[rr].x + sc*acc2[rr].x + tc*alast.x + bo.x)*m;
      v.y = (acc1[rr].y + sc*acc2[rr].y + tc*alast.y + bo.y)*m;
      v.z = (acc1[rr].z + sc*acc2[rr].z + tc*alast.z + bo.z)*m;
      v.w = (acc1[rr].w + sc*acc2[rr].w + tc*alast.w + bo.w)*m;
      res[rr].x = fast_tanh(go.x*(v.x*INV_S) + be.x);
      res[rr].y = fast_tanh(go.y*(v.y*INV_S) + be.y);
      res[rr].z = fast_tanh(go.z*(v.z*INV_S) + be.z);
      res[rr].w = fast_tanh(go.w*(v.w*INV_S) + be.w);
    }
    __syncthreads();   // all xt reads of this layer complete

    if (L < 4){
#pragma unroll
      for (int rr=0;rr<4;rr++){
        int lr = lr0 + rr;
        *(float4*)&xt[lr*68 + o0] = res[rr];                // in-place x
        if (o0 == 60) cb_out[rbase + row0 + lr] = res[rr];  // coords -> global
      }
      __threadfence();
      __syncthreads();
      if (tid == 0)
        __hip_atomic_store(&flags[g], L+1, __ATOMIC_RELEASE,
                           __HIP_MEMORY_SCOPE_AGENT);
    } else {
#pragma unroll
      for (int rr=0;rr<4;rr++){
        int r = rbase + row0 + lr0 + rr;
        *(float4*)&xA[(size_t)r*64 + o0] = res[rr];         // x5 -> global
      }
    }
  }
}

// ---------------------------------------------------------------------------
// dense0 split-K partials. X = xA viewed as (64, 32768) row-major. Block =
// k-chunk of 128, all 64 rows x 128 cols. Thread: 4 rows x 8 cols.
// ---------------------------------------------------------------------------
__global__ __launch_bounds__(256) void dense0_partial(
    const float* __restrict__ X, const float* __restrict__ W,
    float* __restrict__ partial)
{
  __shared__ float xt[64*32];
  __shared__ float wt[32*128];
  int tid = threadIdx.x;
  int k0 = blockIdx.x*128;
  int og = (tid & 15)*8;
  int rg = (tid >> 4)*4;
  float acc[4][8];
#pragma unroll
  for (int a=0;a<4;a++)
#pragma unroll
    for (int u=0;u<8;u++) acc[a][u]=0.f;
  for (int kt = 0; kt < 128; kt += 32){
    __syncthreads();
    for (int idx = tid; idx < 512; idx += 256){
      int r = idx >> 3, kq = idx & 7;
      *(float4*)&xt[r*32 + kq*4] =
          *(const float4*)&X[(size_t)r*32768 + k0 + kt + kq*4];
    }
    {
      const float4* Wc = (const float4*)&W[(size_t)(k0+kt)*128];
      float4* wt4 = (float4*)wt;
      for (int idx = tid; idx < 1024; idx += 256) wt4[idx] = Wc[idx];
    }
    __syncthreads();
#pragma unroll 4
    for (int k=0;k<32;k++){
      float4 w0 = *(const float4*)&wt[k*128 + og];
      float4 w1 = *(const float4*)&wt[k*128 + og + 4];
      float xs[4];
#pragma unroll
      for (int rr=0;rr<4;rr++) xs[rr] = xt[(rg+rr)*32 + k];
#pragma unroll
      for (int rr=0;rr<4;rr++){
        acc[rr][0] = fmaf(xs[rr], w0.x, acc[rr][0]);
        acc[rr][1] = fmaf(xs[rr], w0.y, acc[rr][1]);
        acc[rr][2] = fmaf(xs[rr], w0.z, acc[rr][2]);
        acc[rr][3] = fmaf(xs[rr], w0.w, acc[rr][3]);
        acc[rr][4] = fmaf(xs[rr], w1.x, acc[rr][4]);
        acc[rr][5] = fmaf(xs[rr], w1.y, acc[rr][5]);
        acc[rr][6] = fmaf(xs[rr], w1.z, acc[rr][6]);
        acc[rr][7] = fmaf(xs[rr], w1.w, acc[rr][7]);
      }
    }
  }
  float* pb = partial + (size_t)blockIdx.x*8192;
#pragma unroll
  for (int rr=0;rr<4;rr++){
    *(float4*)&pb[(rg+rr)*128 + og]     = *(float4*)&acc[rr][0];
    *(float4*)&pb[(rg+rr)*128 + og + 4] = *(float4*)&acc[rr][4];
  }
}

// ---------------------------------------------------------------------------
// Head: reduce 256 partials -> bn+sigmoid -> h; GEMV 128x128 -> bn+sigmoid
// -> @W2 + b2 -> out (B,4). One block per batch row.
// ---------------------------------------------------------------------------
__global__ __launch_bounds__(256) void dense_head(
    const float* __restrict__ partial,
    const float* __restrict__ db0, const float* __restrict__ dg0,
    const float* __restrict__ dbb0,
    const float* __restrict__ dW1, const float* __restrict__ db1,
    const float* __restrict__ dg1, const float* __restrict__ dbb1,
    const float* __restrict__ W2, const float* __restrict__ b2,
    float* __restrict__ out)
{
  __shared__ float sred[256];
  __shared__ float h[128];
  __shared__ float red0[128], red1[128];
  int tid = threadIdx.x;
  int b = blockIdx.x;
  int o = tid & 127, ph = tid >> 7;
  float s = 0.f;
#pragma unroll 16
  for (int p = ph*128; p < ph*128+128; p++)
    s += partial[(size_t)p*8192 + b*128 + o];
  sred[tid] = s;
  __syncthreads();
  if (tid < 128){
    float sum = sred[tid] + sred[tid+128];
    float v = dg0[tid]*((sum + db0[tid])*INV_S) + dbb0[tid];
    h[tid] = fast_sigmoid(v);
  }
  __syncthreads();
  if (tid < 128){
    float acc = 0.f;
#pragma unroll 8
    for (int k=0;k<128;k++) acc = fmaf(h[k], dW1[k*128 + tid], acc);
    float v = dg1[tid]*((acc + db1[tid])*INV_S) + dbb1[tid];
    float h1 = fast_sigmoid(v);
    red0[tid] = h1 * W2[tid*2+0];
    red1[tid] = h1 * W2[tid*2+1];
  }
  __syncthreads();
  for (int st=64; st>0; st>>=1){
    if (tid < st){ red0[tid] += red0[tid+st]; red1[tid] += red1[tid+st]; }
    __syncthreads();
  }
  if (tid == 0){
    out[b*4+0] = red0[0] + b2[0];
    out[b*4+1] = red1[0] + b2[1];
    out[b*4+2] = 0.f;
    out[b*4+3] = 0.f;
  }
}

// ---------------------------------------------------------------------------
extern "C" void kernel_launch(void* const* d_in, const int* in_sizes, int n_in,
                              void* d_out, int out_size, void* d_ws, size_t ws_size,
                              hipStream_t stream)
{
  const float* xx   = (const float*)d_in[0];
  const float* emb1 = (const float*)d_in[1];
  const float* emb2 = (const float*)d_in[2];
  const float* emb3 = (const float*)d_in[3];
  const float* A0   = (const float*)d_in[4];
  const float* b0   = (const float*)d_in[5];
  const float* Ar   = (const float*)d_in[6];   // (4,129,64)
  const float* br   = (const float*)d_in[7];   // (4,64)
  const float* bng  = (const float*)d_in[8];   // (5,64)
  const float* bnb  = (const float*)d_in[9];   // (5,64)
  const float* dW0  = (const float*)d_in[10];  // (32768,128)
  const float* db0  = (const float*)d_in[11];
  const float* dW1  = (const float*)d_in[12];  // (128,128)
  const float* db1  = (const float*)d_in[13];
  const float* dbg  = (const float*)d_in[14];  // (2,128)
  const float* dbb  = (const float*)d_in[15];
  const float* W2   = (const float*)d_in[16];  // (128,2)
  const float* b2   = (const float*)d_in[17];

  float* ws = (float*)d_ws;
  float*  xA      = ws;                              // 32768*64
  float*  partial = xA + (size_t)R_*64;              // 256*8192
  float4* cbuf    = (float4*)(partial + (size_t)256*8192);   // 2*32768 float4
  int*    flags   = (int*)(cbuf + (size_t)2*R_);     // 256 ints (poison<0 ok)

  gnn_all<<<256, 512, 0, stream>>>(xx, emb1, emb2, emb3, A0, b0, Ar, br,
                                   bng, bnb, xA, cbuf, flags);
  dense0_partial<<<256, 256, 0, stream>>>(xA, dW0, partial);
  dense_head<<<B_, 256, 0, stream>>>(partial, db0, dbg, dbb,
                                     dW1, db1, dbg + 128, dbb + 128,
                                     W2, b2, (float*)d_out);
}

// Round 10
// 216.715 us; speedup vs baseline: 1.7404x; 1.7404x over previous
//
#include <hip/hip_runtime.h>
#include <math.h>

#define B_ 64
#define N_ 512
#define R_ (B_*N_)                  // 32768 rows
#define INV_S 0.9995003746877732f   // 1/sqrt(1+1e-3)

__device__ __forceinline__ float fast_tanh(float y){
  return 1.f - 2.f*__builtin_amdgcn_rcpf(1.f + __expf(2.f*y));
}
__device__ __forceinline__ float fast_sigmoid(float v){
  return __builtin_amdgcn_rcpf(1.f + __expf(-v));
}

// ---------------------------------------------------------------------------
// GNN layer, 512 threads/block (8 waves), grid (8,64) = 512 blocks ->
// 2 blocks/CU x 8 waves = 16 waves/CU (4/SIMD; round 8 had 8/CU).
// No cl[] LDS: S/T reads ci via wave-uniform loads (uniform loop index into
// compact cbuf for L>=1, or xx for L0 -> scalar pipe), cj via one coalesced
// per-lane load. Only TWO __syncthreads per layer.
// cbuf is DOUBLE-BUFFERED across layers (round 8 read+wrote one buffer in
// the same dispatch -> latent race).
// GEMM: thread = 2 rows x 4 outs x 2 mats; A lo/hi in LDS; x from global
// (block-private rows -> L1) for L>=1, from small LDS tile for L0.
// ---------------------------------------------------------------------------
template<int L0>
__global__ __launch_bounds__(512, 4) void gnn_layer(
    const float* __restrict__ xx, const float* __restrict__ xin,
    const float4* __restrict__ cin, const float* __restrict__ A,
    const float* __restrict__ bias, const float* __restrict__ gamma,
    const float* __restrict__ beta,
    const float* __restrict__ emb1, const float* __restrict__ emb2,
    const float* __restrict__ emb3,
    const float* __restrict__ maskb,     // compact mask in (L>=1)
    float* __restrict__ maskout,         // compact mask out (L0)
    float4* __restrict__ cout,           // compact coords out (null on L4)
    float* __restrict__ xout)
{
  constexpr int KP = L0 ? 36 : 64;
  constexpr int K  = L0 ? 33 : 64;
  __shared__ float alo[KP*64];
  __shared__ float ahi[KP*64];
  __shared__ float xl[L0 ? 64*36 : 4];
  __shared__ float spart[512], tpart[512];
  __shared__ float scl[64], tcl[64], ml[64];

  int tid = threadIdx.x;
  int jc = blockIdx.x;            // 0..7
  int b  = blockIdx.y;            // 0..63
  int rbase = b*N_, jloc = jc*64;

  // ---- stage A lo/hi into LDS ----
  if constexpr (L0){
    for (int idx = tid; idx < KP*64; idx += 512){
      int f = idx >> 6;
      alo[idx] = (f < K) ? A[idx] : 0.f;
      ahi[idx] = (f < K) ? A[(size_t)K*64 + idx] : 0.f;
    }
  } else {
    const float4* A4 = (const float4*)A;
    float4* alo4 = (float4*)alo;
    float4* ahi4 = (float4*)ahi;
    for (int idx = tid; idx < 1024; idx += 512){
      alo4[idx] = A4[idx];
      ahi4[idx] = A4[1024 + idx];
    }
  }

  // ---- L0: build x tile + compact mask; L>=1: load compact mask ----
  if constexpr (L0){
    if (tid < 64){
      int r = rbase + jloc + tid;
      const float* row = xx + (size_t)r*30;
      float v[30];
#pragma unroll
      for (int i=0;i<30;i++) v[i] = row[i];
      int i1 = (int)fabsf(v[27]);
      int i2 = (int)fabsf(v[28]);
      int i3 = (int)fabsf(v[29]);
      float* o = &xl[tid*36];
      o[0]=emb1[i1*2+0]; o[1]=emb1[i1*2+1];
      o[2]=emb2[i2*2+0]; o[3]=emb2[i2*2+1];
      o[4]=emb3[i3*2+0]; o[5]=emb3[i3*2+1];
#pragma unroll
      for (int i=0;i<27;i++) o[6+i] = v[i];
      o[33]=0.f; o[34]=0.f; o[35]=0.f;
      ml[tid] = v[0];
      maskout[r] = v[0];
    }
  } else {
    if (tid < 64) ml[tid] = maskb[rbase + jloc + tid];
  }

  // ---- S/T: jj = tid&63 (row), ic = tid>>6 (one of 8 x 64-i chunks).
  //      ci is wave-uniform per iteration -> scalar-pipe friendly. ----
  {
    int jj = tid & 63, ic = tid >> 6;
    float Ss = 0.f, Ts = 0.f;
    if constexpr (L0){
      const float* xb = xx + (size_t)rbase*30;
      float cjx = xb[(jloc+jj)*30 + 25];
      float cjy = xb[(jloc+jj)*30 + 26];
      int base = ic*64;
#pragma unroll 8
      for (int i=0;i<64;i++){
        float cix = xb[(base+i)*30 + 25];    // uniform address
        float ciy = xb[(base+i)*30 + 26];
        float d0 = cjx-cix, d1 = cjy-ciy;
        float dist = d0*d0 + d1*d1;
        float w = __expf(-10.f*dist);
        Ss += w; Ts += dist*w;
      }
    } else {
      const float4* cb = cin + rbase;
      float4 cj = cb[jloc + jj];
      int base = ic*64;
#pragma unroll 8
      for (int i=0;i<64;i++){
        float4 ci = cb[base+i];              // uniform address
        float d0 = cj.x-ci.x, d1 = cj.y-ci.y, d2 = cj.z-ci.z, d3 = cj.w-ci.w;
        float dist = d0*d0 + d1*d1 + d2*d2 + d3*d3;
        float w = __expf(-10.f*dist);
        Ss += w; Ts += dist*w;
      }
    }
    spart[tid] = Ss;
    tpart[tid] = Ts;
  }
  __syncthreads();     // spart/tpart ready; also covers A/xl/ml staging

  if (tid < 64){
    float S = 0.f, T = 0.f;
#pragma unroll
    for (int c=0;c<8;c++){
      S += spart[tid + 64*c];
      T += tpart[tid + 64*c];
    }
    float m = ml[tid];
    scl[tid] = m*S - 1.f;
    tcl[tid] = m*T;
  }
  __syncthreads();

  // ---- GEMM: thread = 2 rows x 4 outs, two matrices ----
  int cg = tid & 15, rg = tid >> 4;        // cg 0..15, rg 0..31
  int o0 = cg*4, lr0 = rg*2;
  const float* xb2 = xin + (size_t)(rbase + jloc)*64;   // L>=1 only
  float4 acc1[2], acc2[2];
#pragma unroll
  for (int rr=0;rr<2;rr++){
    acc1[rr] = make_float4(0.f,0.f,0.f,0.f);
    acc2[rr] = make_float4(0.f,0.f,0.f,0.f);
  }
#pragma unroll 2
  for (int kc = 0; kc < KP; kc += 4){
    float4 a1[4], a2[4], xv[2];
#pragma unroll
    for (int uu=0;uu<4;uu++){
      a1[uu] = *(const float4*)&alo[(kc+uu)*64 + o0];
      a2[uu] = *(const float4*)&ahi[(kc+uu)*64 + o0];
    }
#pragma unroll
    for (int rr=0;rr<2;rr++){
      if constexpr (L0) xv[rr] = *(const float4*)&xl[(lr0+rr)*36 + kc];
      else              xv[rr] = *(const float4*)&xb2[(lr0+rr)*64 + kc];
    }
#pragma unroll
    for (int uu=0;uu<4;uu++){
#pragma unroll
      for (int rr=0;rr<2;rr++){
        float xu = ((const float*)&xv[rr])[uu];
        acc1[rr].x = fmaf(xu, a1[uu].x, acc1[rr].x);
        acc1[rr].y = fmaf(xu, a1[uu].y, acc1[rr].y);
        acc1[rr].z = fmaf(xu, a1[uu].z, acc1[rr].z);
        acc1[rr].w = fmaf(xu, a1[uu].w, acc1[rr].w);
        acc2[rr].x = fmaf(xu, a2[uu].x, acc2[rr].x);
        acc2[rr].y = fmaf(xu, a2[uu].y, acc2[rr].y);
        acc2[rr].z = fmaf(xu, a2[uu].z, acc2[rr].z);
        acc2[rr].w = fmaf(xu, a2[uu].w, acc2[rr].w);
      }
    }
  }

  float4 alast = *(const float4*)&A[(size_t)2*K*64 + o0];
  float4 bo = *(const float4*)&bias[o0];
  float4 go = *(const float4*)&gamma[o0];
  float4 be = *(const float4*)&beta[o0];
#pragma unroll
  for (int rr=0;rr<2;rr++){
    int lr = lr0 + rr;
    int r = rbase + jloc + lr;
    float sc = scl[lr], tc = tcl[lr], m = ml[lr];
    float4 v;
    v.x = (acc1[rr].x + sc*acc2[rr].x + tc*alast.x + bo.x)*m;
    v.y = (acc1[rr].y + sc*acc2[rr].y + tc*alast.y + bo.y)*m;
    v.z = (acc1[rr].z + sc*acc2[rr].z + tc*alast.z + bo.z)*m;
    v.w = (acc1[rr].w + sc*acc2[rr].w + tc*alast.w + bo.w)*m;
    float4 t;
    t.x = fast_tanh(go.x*(v.x*INV_S) + be.x);
    t.y = fast_tanh(go.y*(v.y*INV_S) + be.y);
    t.z = fast_tanh(go.z*(v.z*INV_S) + be.z);
    t.w = fast_tanh(go.w*(v.w*INV_S) + be.w);
    *(float4*)&xout[(size_t)r*64 + o0] = t;
    if (cout && cg == 15) cout[r] = t;     // compact coords (double-buffered)
  }
}

// ---------------------------------------------------------------------------
// dense0 split-K partials (unchanged from round 8).
// ---------------------------------------------------------------------------
__global__ __launch_bounds__(256) void dense0_partial(
    const float* __restrict__ X, const float* __restrict__ W,
    float* __restrict__ partial)
{
  __shared__ float xt[64*32];
  __shared__ float wt[32*128];
  int tid = threadIdx.x;
  int k0 = blockIdx.x*128;
  int og = (tid & 15)*8;
  int rg = (tid >> 4)*4;
  float acc[4][8];
#pragma unroll
  for (int a=0;a<4;a++)
#pragma unroll
    for (int u=0;u<8;u++) acc[a][u]=0.f;
  for (int kt = 0; kt < 128; kt += 32){
    __syncthreads();
    for (int idx = tid; idx < 512; idx += 256){
      int r = idx >> 3, kq = idx & 7;
      *(float4*)&xt[r*32 + kq*4] =
          *(const float4*)&X[(size_t)r*32768 + k0 + kt + kq*4];
    }
    {
      const float4* Wc = (const float4*)&W[(size_t)(k0+kt)*128];
      float4* wt4 = (float4*)wt;
      for (int idx = tid; idx < 1024; idx += 256) wt4[idx] = Wc[idx];
    }
    __syncthreads();
#pragma unroll 4
    for (int k=0;k<32;k++){
      float4 w0 = *(const float4*)&wt[k*128 + og];
      float4 w1 = *(const float4*)&wt[k*128 + og + 4];
      float xs[4];
#pragma unroll
      for (int rr=0;rr<4;rr++) xs[rr] = xt[(rg+rr)*32 + k];
#pragma unroll
      for (int rr=0;rr<4;rr++){
        acc[rr][0] = fmaf(xs[rr], w0.x, acc[rr][0]);
        acc[rr][1] = fmaf(xs[rr], w0.y, acc[rr][1]);
        acc[rr][2] = fmaf(xs[rr], w0.z, acc[rr][2]);
        acc[rr][3] = fmaf(xs[rr], w0.w, acc[rr][3]);
        acc[rr][4] = fmaf(xs[rr], w1.x, acc[rr][4]);
        acc[rr][5] = fmaf(xs[rr], w1.y, acc[rr][5]);
        acc[rr][6] = fmaf(xs[rr], w1.z, acc[rr][6]);
        acc[rr][7] = fmaf(xs[rr], w1.w, acc[rr][7]);
      }
    }
  }
  float* pb = partial + (size_t)blockIdx.x*8192;
#pragma unroll
  for (int rr=0;rr<4;rr++){
    *(float4*)&pb[(rg+rr)*128 + og]     = *(float4*)&acc[rr][0];
    *(float4*)&pb[(rg+rr)*128 + og + 4] = *(float4*)&acc[rr][4];
  }
}

// ---------------------------------------------------------------------------
// Head (unchanged from round 8).
// ---------------------------------------------------------------------------
__global__ __launch_bounds__(256) void dense_head(
    const float* __restrict__ partial,
    const float* __restrict__ db0, const float* __restrict__ dg0,
    const float* __restrict__ dbb0,
    const float* __restrict__ dW1, const float* __restrict__ db1,
    const float* __restrict__ dg1, const float* __restrict__ dbb1,
    const float* __restrict__ W2, const float* __restrict__ b2,
    float* __restrict__ out)
{
  __shared__ float sred[256];
  __shared__ float h[128];
  __shared__ float red0[128], red1[128];
  int tid = threadIdx.x;
  int b = blockIdx.x;
  int o = tid & 127, ph = tid >> 7;
  float s = 0.f;
#pragma unroll 16
  for (int p = ph*128; p < ph*128+128; p++)
    s += partial[(size_t)p*8192 + b*128 + o];
  sred[tid] = s;
  __syncthreads();
  if (tid < 128){
    float sum = sred[tid] + sred[tid+128];
    float v = dg0[tid]*((sum + db0[tid])*INV_S) + dbb0[tid];
    h[tid] = fast_sigmoid(v);
  }
  __syncthreads();
  if (tid < 128){
    float acc = 0.f;
#pragma unroll 8
    for (int k=0;k<128;k++) acc = fmaf(h[k], dW1[k*128 + tid], acc);
    float v = dg1[tid]*((acc + db1[tid])*INV_S) + dbb1[tid];
    float h1 = fast_sigmoid(v);
    red0[tid] = h1 * W2[tid*2+0];
    red1[tid] = h1 * W2[tid*2+1];
  }
  __syncthreads();
  for (int st=64; st>0; st>>=1){
    if (tid < st){ red0[tid] += red0[tid+st]; red1[tid] += red1[tid+st]; }
    __syncthreads();
  }
  if (tid == 0){
    out[b*4+0] = red0[0] + b2[0];
    out[b*4+1] = red1[0] + b2[1];
    out[b*4+2] = 0.f;
    out[b*4+3] = 0.f;
  }
}

// ---------------------------------------------------------------------------
extern "C" void kernel_launch(void* const* d_in, const int* in_sizes, int n_in,
                              void* d_out, int out_size, void* d_ws, size_t ws_size,
                              hipStream_t stream)
{
  const float* xx   = (const float*)d_in[0];
  const float* emb1 = (const float*)d_in[1];
  const float* emb2 = (const float*)d_in[2];
  const float* emb3 = (const float*)d_in[3];
  const float* A0   = (const float*)d_in[4];
  const float* b0   = (const float*)d_in[5];
  const float* Ar   = (const float*)d_in[6];   // (4,129,64)
  const float* br   = (const float*)d_in[7];   // (4,64)
  const float* bng  = (const float*)d_in[8];   // (5,64)
  const float* bnb  = (const float*)d_in[9];   // (5,64)
  const float* dW0  = (const float*)d_in[10];  // (32768,128)
  const float* db0  = (const float*)d_in[11];
  const float* dW1  = (const float*)d_in[12];  // (128,128)
  const float* db1  = (const float*)d_in[13];
  const float* dbg  = (const float*)d_in[14];  // (2,128)
  const float* dbb  = (const float*)d_in[15];
  const float* W2   = (const float*)d_in[16];  // (128,2)
  const float* b2   = (const float*)d_in[17];

  float* ws = (float*)d_ws;
  float*  xA      = ws;                              // 32768*64
  float*  xB      = xA + (size_t)R_*64;              // 32768*64
  float*  partial = xB + (size_t)R_*64;              // 256*8192
  float*  maskb   = partial + (size_t)256*8192;      // 32768
  float4* cb0     = (float4*)(maskb + R_);           // 32768 float4
  float4* cb1     = cb0 + R_;                        // 32768 float4

  dim3 lgrid(8, 64);
  // L0: xx -> xA, coords -> cb1, mask -> maskb
  gnn_layer<1><<<lgrid, 512, 0, stream>>>(
      xx, nullptr, nullptr, A0, b0, bng, bnb, emb1, emb2, emb3,
      nullptr, maskb, cb1, xA);
  // L1: xA -> xB, cb1 -> cb0
  gnn_layer<0><<<lgrid, 512, 0, stream>>>(
      xx, xA, cb1, Ar + (size_t)0*129*64, br + 0*64, bng + 64, bnb + 64,
      emb1, emb2, emb3, maskb, nullptr, cb0, xB);
  // L2: xB -> xA, cb0 -> cb1
  gnn_layer<0><<<lgrid, 512, 0, stream>>>(
      xx, xB, cb0, Ar + (size_t)1*129*64, br + 1*64, bng + 128, bnb + 128,
      emb1, emb2, emb3, maskb, nullptr, cb1, xA);
  // L3: xA -> xB, cb1 -> cb0
  gnn_layer<0><<<lgrid, 512, 0, stream>>>(
      xx, xA, cb1, Ar + (size_t)2*129*64, br + 2*64, bng + 192, bnb + 192,
      emb1, emb2, emb3, maskb, nullptr, cb0, xB);
  // L4: xB -> xA, coords not needed further
  gnn_layer<0><<<lgrid, 512, 0, stream>>>(
      xx, xB, cb0, Ar + (size_t)3*129*64, br + 3*64, bng + 256, bnb + 256,
      emb1, emb2, emb3, maskb, nullptr, nullptr, xA);

  dense0_partial<<<256, 256, 0, stream>>>(xA, dW0, partial);
  dense_head<<<B_, 256, 0, stream>>>(partial, db0, dbg, dbb,
                                     dW1, db1, dbg + 128, dbb + 128,
                                     W2, b2, (float*)d_out);
}